// Round 6
// baseline (651.684 us; speedup 1.0000x reference)
//
#include <hip/hip_runtime.h>
#include <math.h>

// Problem constants
#define NROWS 16384   // 32*512
#define H     768
#define KEXP  6912    // 768 (silu*base_w) + 768*8 (bases*spline_w*scaler)
#define NCHUNK 108    // KEXP/64

typedef __attribute__((ext_vector_type(8))) short  bhalf8;
typedef __attribute__((ext_vector_type(4))) float  floatx4;

__device__ __forceinline__ unsigned short f2bf(float f) {
    unsigned int u = __float_as_uint(f);
    u = (u + 0x7FFFu + ((u >> 16) & 1u)) >> 16;   // RNE
    return (unsigned short)u;
}
__device__ __forceinline__ unsigned int pack2(unsigned short a, unsigned short b) {
    return (unsigned int)a | ((unsigned int)b << 16);
}
__device__ __forceinline__ float silu_f(float x) { return x / (1.0f + __expf(-x)); }
__device__ __forceinline__ float gelu_exact(float x) {
    return 0.5f * x * (1.0f + erff(x * 0.70710678118654752f));
}

// Closed-form cubic B-spline bases on uniform knots g[j] = (j-3)*0.4 - 1.
// (round-4-verified: identical absmax to Cox-de-Boor recursion)
__device__ __forceinline__ void kan_bases(float x, float* __restrict__ b) {
    const float c6 = 0.166666666667f;
    float u  = fmaf(x, 2.5f, 5.5f);      // (x + 2.2) / 0.4
    float fj = floorf(u);
    float t  = u - fj;                    // in [0,1)
    int  j0  = (int)fj;
    float t2 = t * t, t3 = t2 * t;
    float n0 = t3 * c6;
    float n1 = fmaf(t3, -0.5f, fmaf(t2, 0.5f, fmaf(t, 0.5f, c6)));
    float n2 = fmaf(t3, 0.5f, fmaf(t2, -1.0f, 0.666666666667f));
    float omt = 1.0f - t;
    float n3 = omt * omt * omt * c6;
#pragma unroll
    for (int c = 0; c < 8; ++c) {
        int d = j0 - c;
        float v = (d == 0) ? n0 : 0.0f;
        v = (d == 1) ? n1 : v;
        v = (d == 2) ? n2 : v;
        v = (d == 3) ? n3 : v;
        b[c] = v;
    }
}

// ---- Merged prep: W' bf16 [768][6912] (blocks 0..767) and
//      F bf16 [16384][6912] (blocks 768..17151).
__global__ __launch_bounds__(256) void prep_expand(
    const float* __restrict__ x, const float* __restrict__ bw,
    const float* __restrict__ sw, const float* __restrict__ sc,
    unsigned short* __restrict__ wp, unsigned short* __restrict__ F)
{
    const int b = blockIdx.x, t = threadIdx.x;
    if (b < H) {
        // W' row b = [ bw1[b][:] | sw1[b][i][c]*sc1[b][i] ]
        const int n = b;
        const float* bwr = bw + (size_t)n * H;
        unsigned short* out = wp + (size_t)n * KEXP;
        for (int k = t; k < H; k += 256) out[k] = f2bf(bwr[k]);
#pragma unroll
        for (int p = 0; p < 3; ++p) {
            int i = t + p * 256;
            float s = sc[(size_t)n * H + i];
            const float4* swp = (const float4*)(sw + ((size_t)n * H + i) * 8);
            float4 w0 = swp[0], w1 = swp[1];
            uint4 pk;
            pk.x = pack2(f2bf(w0.x * s), f2bf(w0.y * s));
            pk.y = pack2(f2bf(w0.z * s), f2bf(w0.w * s));
            pk.z = pack2(f2bf(w1.x * s), f2bf(w1.y * s));
            pk.w = pack2(f2bf(w1.z * s), f2bf(w1.w * s));
            *(uint4*)(out + H + (size_t)i * 8) = pk;
        }
    } else {
        // F row n = [ silu(x[n][:]) | bases(x[n][i])[8] ]
        const int n = b - H;
        unsigned short* out = F + (size_t)n * KEXP;
#pragma unroll
        for (int p = 0; p < 3; ++p) {
            int i = t + p * 256;
            float xv = x[(size_t)n * H + i];
            out[i] = f2bf(silu_f(xv));
            float bb[8];
            kan_bases(xv, bb);
            uint4 pk;
            pk.x = pack2(f2bf(bb[0]), f2bf(bb[1]));
            pk.y = pack2(f2bf(bb[2]), f2bf(bb[3]));
            pk.z = pack2(f2bf(bb[4]), f2bf(bb[5]));
            pk.w = pack2(f2bf(bb[6]), f2bf(bb[7]));
            *(uint4*)(out + H + (size_t)i * 8) = pk;
        }
    }
}

// ---- Layer 1 GEMM + fused layer 2:
// pure bf16 MFMA GEMM (A=F, B=W', global_load_lds, XOR swizzle, XCD swizzle —
// all r2-r4 verified), then epilogue: u = gelu(h) in fp32, kan features of u,
// dot with layer-2 weight slice (10KB per col-tile, L1-resident), LDS reduce
// per row, one global atomicAdd per (row,out) per block (6 adds/address total).
__global__ __launch_bounds__(256) void kan1_gemm(
    const unsigned short* __restrict__ F, const unsigned short* __restrict__ wp,
    const float* __restrict__ bw2, const float* __restrict__ sw2,
    const float* __restrict__ sc2, float* __restrict__ out)
{
    __shared__ __align__(16) unsigned short sA[128 * 64];
    __shared__ __align__(16) unsigned short sB[128 * 64];
    __shared__ float sOut[256];               // 128 rows x 2 outputs
    const int b = blockIdx.x;                 // 0..767
    const int xcd = b & 7, s = b >> 3;        // s in 0..95
    const int rowT = xcd * 16 + s / 6;
    const int colT = s % 6;
    const int rowBase = rowT * 128, colBase = colT * 128;

    const int t = threadIdx.x;
    const int lane = t & 63, wv = t >> 6;
    const int quad = lane >> 4, lm = lane & 15;
    const int wr = wv & 1, wc = wv >> 1;
    const int p7 = lm & 7;

    sOut[t] = 0.0f;

    floatx4 acc[4][4] = {};
    int aoff[4], boff[4], goff[2];
#pragma unroll
    for (int im = 0; im < 4; ++im) aoff[im] = (wr * 64 + im * 16 + lm) * 64;
#pragma unroll
    for (int in_ = 0; in_ < 4; ++in_) boff[in_] = (wc * 64 + in_ * 16 + lm) * 64;
#pragma unroll
    for (int kk = 0; kk < 2; ++kk) goff[kk] = ((kk * 4 + quad) ^ p7) * 8;

    const int br_off = lane >> 3;   // row within 8-row segment
    const int bg_slot = lane & 7;   // lds granule slot

#pragma unroll 1
    for (int kc = 0; kc < NCHUNK; ++kc) {
#pragma unroll
        for (int p = 0; p < 4; ++p) {
            int sseg = wv * 4 + p;
            int r = sseg * 8 + br_off;
            int g = bg_slot ^ (r & 7);
            const unsigned short* ga = F  + (size_t)(rowBase + r) * KEXP + kc * 64 + g * 8;
            const unsigned short* gb = wp + (size_t)(colBase + r) * KEXP + kc * 64 + g * 8;
            __builtin_amdgcn_global_load_lds(
                (const __attribute__((address_space(1))) void*)ga,
                (__attribute__((address_space(3))) void*)(sA + sseg * 512), 16, 0, 0);
            __builtin_amdgcn_global_load_lds(
                (const __attribute__((address_space(1))) void*)gb,
                (__attribute__((address_space(3))) void*)(sB + sseg * 512), 16, 0, 0);
        }
        __syncthreads();
#pragma unroll
        for (int kk = 0; kk < 2; ++kk) {
            bhalf8 af[4], bf[4];
#pragma unroll
            for (int im = 0; im < 4; ++im) af[im] = *(const bhalf8*)&sA[aoff[im] + goff[kk]];
#pragma unroll
            for (int in_ = 0; in_ < 4; ++in_) bf[in_] = *(const bhalf8*)&sB[boff[in_] + goff[kk]];
#pragma unroll
            for (int im = 0; im < 4; ++im)
#pragma unroll
                for (int in_ = 0; in_ < 4; ++in_)
                    acc[im][in_] = __builtin_amdgcn_mfma_f32_16x16x32_bf16(
                        af[im], bf[in_], acc[im][in_], 0, 0, 0);
        }
        __syncthreads();
    }

    // ---- fused layer-2 epilogue ----
    float p0[4][4] = {}, p1[4][4] = {};
#pragma unroll
    for (int in_ = 0; in_ < 4; ++in_) {
        int col = colBase + wc * 64 + in_ * 16 + lm;   // layer-2 input channel
        float b0 = bw2[col],     b1 = bw2[H + col];
        float s0 = sc2[col],     s1 = sc2[H + col];
        const float4* q0 = (const float4*)(sw2 + (size_t)col * 8);
        const float4* q1 = (const float4*)(sw2 + (size_t)(H + col) * 8);
        float4 w00 = q0[0], w01 = q0[1];
        float4 w10 = q1[0], w11 = q1[1];
#pragma unroll
        for (int im = 0; im < 4; ++im)
#pragma unroll
            for (int reg = 0; reg < 4; ++reg) {
                float u = gelu_exact(acc[im][in_][reg]);
                float f0 = silu_f(u);
                float bb[8];
                kan_bases(u, bb);
                float t0 = bb[0]*w00.x + bb[1]*w00.y + bb[2]*w00.z + bb[3]*w00.w
                         + bb[4]*w01.x + bb[5]*w01.y + bb[6]*w01.z + bb[7]*w01.w;
                float t1 = bb[0]*w10.x + bb[1]*w10.y + bb[2]*w10.z + bb[3]*w10.w
                         + bb[4]*w11.x + bb[5]*w11.y + bb[6]*w11.z + bb[7]*w11.w;
                p0[im][reg] += f0 * b0 + s0 * t0;
                p1[im][reg] += f0 * b1 + s1 * t1;
            }
    }
#pragma unroll
    for (int im = 0; im < 4; ++im)
#pragma unroll
        for (int reg = 0; reg < 4; ++reg) {
            int r = wr * 64 + im * 16 + quad * 4 + reg;
            atomicAdd(&sOut[r * 2 + 0], p0[im][reg]);
            atomicAdd(&sOut[r * 2 + 1], p1[im][reg]);
        }
    __syncthreads();
    // one global atomic per (row,out) per block; 6 blocks contribute per address
    atomicAdd(out + (size_t)(rowBase + (t >> 1)) * 2 + (t & 1), sOut[t]);
}

extern "C" void kernel_launch(void* const* d_in, const int* in_sizes, int n_in,
                              void* d_out, int out_size, void* d_ws, size_t ws_size,
                              hipStream_t stream) {
    const float* hidden = (const float*)d_in[0];
    const float* bw1    = (const float*)d_in[1];
    const float* sw1    = (const float*)d_in[2];
    const float* sc1    = (const float*)d_in[3];
    const float* bw2    = (const float*)d_in[4];
    const float* sw2    = (const float*)d_in[5];
    const float* sc2    = (const float*)d_in[6];
    float* out = (float*)d_out;

    const size_t wp_elems = (size_t)H * KEXP;      // 10.6 MB bf16
    unsigned short* wp = (unsigned short*)d_ws;
    unsigned short* F  = wp + wp_elems;            // 226.5 MB bf16

    hipMemsetAsync(out, 0, (size_t)out_size * sizeof(float), stream);
    prep_expand<<<H + NROWS, 256, 0, stream>>>(hidden, bw1, sw1, sc1, wp, F);
    kan1_gemm<<<768, 256, 0, stream>>>(F, wp, bw2, sw2, sc2, out);
}

// Round 7
// 567.450 us; speedup vs baseline: 1.1484x; 1.1484x over previous
//
#include <hip/hip_runtime.h>
#include <math.h>

// Problem constants
#define NROWS 16384   // 32*512
#define H     768
#define KEXP  6912    // 768 (silu*base_w) + 768*8 (bases*spline_w*scaler)
#define NCHUNK 108    // KEXP/64

typedef __attribute__((ext_vector_type(8))) short  bhalf8;
typedef __attribute__((ext_vector_type(4))) float  floatx4;

__device__ __forceinline__ unsigned short f2bf(float f) {
    unsigned int u = __float_as_uint(f);
    u = (u + 0x7FFFu + ((u >> 16) & 1u)) >> 16;   // RNE
    return (unsigned short)u;
}
__device__ __forceinline__ float bf2f(unsigned short h) {
    return __uint_as_float(((unsigned int)h) << 16);
}
__device__ __forceinline__ unsigned int pack2(unsigned short a, unsigned short b) {
    return (unsigned int)a | ((unsigned int)b << 16);
}
__device__ __forceinline__ float silu_f(float x) { return x / (1.0f + __expf(-x)); }
__device__ __forceinline__ float gelu_exact(float x) {
    return 0.5f * x * (1.0f + erff(x * 0.70710678118654752f));
}

// Closed-form cubic B-spline bases on uniform knots g[j] = (j-3)*0.4 - 1.
// (round-4-verified: identical absmax to Cox-de-Boor recursion)
__device__ __forceinline__ void kan_bases(float x, float* __restrict__ b) {
    const float c6 = 0.166666666667f;
    float u  = fmaf(x, 2.5f, 5.5f);      // (x + 2.2) / 0.4
    float fj = floorf(u);
    float t  = u - fj;                    // in [0,1)
    int  j0  = (int)fj;
    float t2 = t * t, t3 = t2 * t;
    float n0 = t3 * c6;
    float n1 = fmaf(t3, -0.5f, fmaf(t2, 0.5f, fmaf(t, 0.5f, c6)));
    float n2 = fmaf(t3, 0.5f, fmaf(t2, -1.0f, 0.666666666667f));
    float omt = 1.0f - t;
    float n3 = omt * omt * omt * c6;
#pragma unroll
    for (int c = 0; c < 8; ++c) {
        int d = j0 - c;
        float v = (d == 0) ? n0 : 0.0f;
        v = (d == 1) ? n1 : v;
        v = (d == 2) ? n2 : v;
        v = (d == 3) ? n3 : v;
        b[c] = v;
    }
}

// ---- Merged prep: W' bf16 [768][6912] (blocks 0..767) and
//      F bf16 [16384][6912] (blocks 768..17151).  (R6-verified, ~90us)
__global__ __launch_bounds__(256) void prep_expand(
    const float* __restrict__ x, const float* __restrict__ bw,
    const float* __restrict__ sw, const float* __restrict__ sc,
    unsigned short* __restrict__ wp, unsigned short* __restrict__ F)
{
    const int b = blockIdx.x, t = threadIdx.x;
    if (b < H) {
        const int n = b;
        const float* bwr = bw + (size_t)n * H;
        unsigned short* out = wp + (size_t)n * KEXP;
        for (int k = t; k < H; k += 256) out[k] = f2bf(bwr[k]);
#pragma unroll
        for (int p = 0; p < 3; ++p) {
            int i = t + p * 256;
            float s = sc[(size_t)n * H + i];
            const float4* swp = (const float4*)(sw + ((size_t)n * H + i) * 8);
            float4 w0 = swp[0], w1 = swp[1];
            uint4 pk;
            pk.x = pack2(f2bf(w0.x * s), f2bf(w0.y * s));
            pk.y = pack2(f2bf(w0.z * s), f2bf(w0.w * s));
            pk.z = pack2(f2bf(w1.x * s), f2bf(w1.y * s));
            pk.w = pack2(f2bf(w1.z * s), f2bf(w1.w * s));
            *(uint4*)(out + H + (size_t)i * 8) = pk;
        }
    } else {
        const int n = b - H;
        unsigned short* out = F + (size_t)n * KEXP;
#pragma unroll
        for (int p = 0; p < 3; ++p) {
            int i = t + p * 256;
            float xv = x[(size_t)n * H + i];
            out[i] = f2bf(silu_f(xv));
            float bb[8];
            kan_bases(xv, bb);
            uint4 pk;
            pk.x = pack2(f2bf(bb[0]), f2bf(bb[1]));
            pk.y = pack2(f2bf(bb[2]), f2bf(bb[3]));
            pk.z = pack2(f2bf(bb[4]), f2bf(bb[5]));
            pk.w = pack2(f2bf(bb[6]), f2bf(bb[7]));
            *(uint4*)(out + H + (size_t)i * 8) = pk;
        }
    }
}

// ---- Layer 1: pure bf16 MFMA GEMM (R4 structure verbatim: VGPR 76, 213us)
// + GELU-only epilogue (R5-verified cheap): stores u = gelu(h) as bf16.
__global__ __launch_bounds__(256) void kan1_gemm(
    const unsigned short* __restrict__ F, const unsigned short* __restrict__ wp,
    unsigned short* __restrict__ l1)
{
    __shared__ __align__(16) unsigned short sA[128 * 64];
    __shared__ __align__(16) unsigned short sB[128 * 64];
    const int b = blockIdx.x;          // 0..767
    const int xcd = b & 7, s = b >> 3; // s in 0..95
    const int rowT = xcd * 16 + s / 6;
    const int colT = s % 6;
    const int rowBase = rowT * 128, colBase = colT * 128;

    const int t = threadIdx.x;
    const int lane = t & 63, wv = t >> 6;
    const int quad = lane >> 4, lm = lane & 15;
    const int wr = wv & 1, wc = wv >> 1;
    const int p7 = lm & 7;

    floatx4 acc[4][4] = {};
    int aoff[4], boff[4], goff[2];
#pragma unroll
    for (int im = 0; im < 4; ++im) aoff[im] = (wr * 64 + im * 16 + lm) * 64;
#pragma unroll
    for (int in_ = 0; in_ < 4; ++in_) boff[in_] = (wc * 64 + in_ * 16 + lm) * 64;
#pragma unroll
    for (int kk = 0; kk < 2; ++kk) goff[kk] = ((kk * 4 + quad) ^ p7) * 8;

    const int br_off = lane >> 3;   // row within 8-row segment
    const int bg_slot = lane & 7;   // lds granule slot

#pragma unroll 1
    for (int kc = 0; kc < NCHUNK; ++kc) {
#pragma unroll
        for (int p = 0; p < 4; ++p) {
            int sseg = wv * 4 + p;
            int r = sseg * 8 + br_off;
            int g = bg_slot ^ (r & 7);
            const unsigned short* ga = F  + (size_t)(rowBase + r) * KEXP + kc * 64 + g * 8;
            const unsigned short* gb = wp + (size_t)(colBase + r) * KEXP + kc * 64 + g * 8;
            __builtin_amdgcn_global_load_lds(
                (const __attribute__((address_space(1))) void*)ga,
                (__attribute__((address_space(3))) void*)(sA + sseg * 512), 16, 0, 0);
            __builtin_amdgcn_global_load_lds(
                (const __attribute__((address_space(1))) void*)gb,
                (__attribute__((address_space(3))) void*)(sB + sseg * 512), 16, 0, 0);
        }
        __syncthreads();
#pragma unroll
        for (int kk = 0; kk < 2; ++kk) {
            bhalf8 af[4], bf[4];
#pragma unroll
            for (int im = 0; im < 4; ++im) af[im] = *(const bhalf8*)&sA[aoff[im] + goff[kk]];
#pragma unroll
            for (int in_ = 0; in_ < 4; ++in_) bf[in_] = *(const bhalf8*)&sB[boff[in_] + goff[kk]];
#pragma unroll
            for (int im = 0; im < 4; ++im)
#pragma unroll
                for (int in_ = 0; in_ < 4; ++in_)
                    acc[im][in_] = __builtin_amdgcn_mfma_f32_16x16x32_bf16(
                        af[im], bf[in_], acc[im][in_], 0, 0, 0);
        }
        __syncthreads();
    }
    // epilogue: u = gelu(h), store bf16
#pragma unroll
    for (int im = 0; im < 4; ++im) {
#pragma unroll
        for (int in_ = 0; in_ < 4; ++in_) {
            int col = colBase + wc * 64 + in_ * 16 + lm;
            size_t rbase = (size_t)(rowBase + wr * 64 + im * 16 + quad * 4);
#pragma unroll
            for (int reg = 0; reg < 4; ++reg)
                l1[(rbase + reg) * H + col] = f2bf(gelu_exact(acc[im][in_][reg]));
        }
    }
}

// ---- Layer 2 (no erf — gelu already applied): 8 rows/block, half-wave per
// row, bhalf8 vector loads of u, width-32 shuffle reduction.
__global__ __launch_bounds__(256) void kan2_kernel(
    const unsigned short* __restrict__ l1, const float* __restrict__ bw,
    const float* __restrict__ sw, const float* __restrict__ sc,
    float* __restrict__ out)
{
    const int t = threadIdx.x;
    const int half = t >> 5;          // 0..7 -> row within block
    const int lane32 = t & 31;
    const int n = blockIdx.x * 8 + half;
    float a0 = 0.f, a1 = 0.f;
#pragma unroll
    for (int it = 0; it < 3; ++it) {
        int c0 = (lane32 + it * 32) * 8;          // channel base (8 per lane)
        bhalf8 v = *(const bhalf8*)&l1[(size_t)n * H + c0];
#pragma unroll
        for (int j = 0; j < 8; ++j) {
            int i = c0 + j;
            float u = bf2f((unsigned short)v[j]);
            float f0 = silu_f(u);
            float bb[8];
            kan_bases(u, bb);
            float bw0 = bw[i], bw1 = bw[H + i];
            float s0 = sc[i], s1 = sc[H + i];
            const float4* q0 = (const float4*)(sw + (size_t)i * 8);
            const float4* q1 = (const float4*)(sw + (size_t)(H + i) * 8);
            float4 w00 = q0[0], w01 = q0[1];
            float4 w10 = q1[0], w11 = q1[1];
            float t0 = bb[0]*w00.x + bb[1]*w00.y + bb[2]*w00.z + bb[3]*w00.w
                     + bb[4]*w01.x + bb[5]*w01.y + bb[6]*w01.z + bb[7]*w01.w;
            float t1 = bb[0]*w10.x + bb[1]*w10.y + bb[2]*w10.z + bb[3]*w10.w
                     + bb[4]*w11.x + bb[5]*w11.y + bb[6]*w11.z + bb[7]*w11.w;
            a0 += f0 * bw0 + s0 * t0;
            a1 += f0 * bw1 + s1 * t1;
        }
    }
    // reduce across the 32 lanes of this half-wave (width-32 shuffles)
#pragma unroll
    for (int off = 16; off > 0; off >>= 1) {
        a0 += __shfl_down(a0, off, 32);
        a1 += __shfl_down(a1, off, 32);
    }
    if (lane32 == 0) {
        out[(size_t)n * 2 + 0] = a0;
        out[(size_t)n * 2 + 1] = a1;
    }
}

extern "C" void kernel_launch(void* const* d_in, const int* in_sizes, int n_in,
                              void* d_out, int out_size, void* d_ws, size_t ws_size,
                              hipStream_t stream) {
    const float* hidden = (const float*)d_in[0];
    const float* bw1    = (const float*)d_in[1];
    const float* sw1    = (const float*)d_in[2];
    const float* sc1    = (const float*)d_in[3];
    const float* bw2    = (const float*)d_in[4];
    const float* sw2    = (const float*)d_in[5];
    const float* sc2    = (const float*)d_in[6];
    float* out = (float*)d_out;

    const size_t wp_elems = (size_t)H * KEXP;      // 10.6 MB bf16
    const size_t f_elems  = (size_t)NROWS * KEXP;  // 226.5 MB bf16
    unsigned short* wp = (unsigned short*)d_ws;
    unsigned short* F  = wp + wp_elems;
    unsigned short* l1 = F + f_elems;              // 25.2 MB bf16

    prep_expand<<<H + NROWS, 256, 0, stream>>>(hidden, bw1, sw1, sc1, wp, F);
    kan1_gemm<<<768, 256, 0, stream>>>(F, wp, l1);
    kan2_kernel<<<NROWS / 8, 256, 0, stream>>>(l1, bw2, sw2, sc2, out);
}

// Round 8
// 454.061 us; speedup vs baseline: 1.4352x; 1.2497x over previous
//
#include <hip/hip_runtime.h>
#include <math.h>

// Problem constants
#define NROWS 16384   // 32*512
#define H     768
#define KEXP  6912    // 768 (silu*base_w) + 768*8 (bases*spline_w*scaler)
#define NCHUNK 108    // KEXP/64

typedef __attribute__((ext_vector_type(8))) short  bhalf8;
typedef __attribute__((ext_vector_type(4))) float  floatx4;

__device__ __forceinline__ unsigned short f2bf(float f) {
    unsigned int u = __float_as_uint(f);
    u = (u + 0x7FFFu + ((u >> 16) & 1u)) >> 16;   // RNE
    return (unsigned short)u;
}
__device__ __forceinline__ float bf2f(unsigned short h) {
    return __uint_as_float(((unsigned int)h) << 16);
}
__device__ __forceinline__ unsigned int pack2(unsigned short a, unsigned short b) {
    return (unsigned int)a | ((unsigned int)b << 16);
}
__device__ __forceinline__ float silu_f(float x) { return x / (1.0f + __expf(-x)); }
__device__ __forceinline__ float gelu_exact(float x) {
    return 0.5f * x * (1.0f + erff(x * 0.70710678118654752f));
}

// Closed-form cubic B-spline bases on uniform knots g[j] = (j-3)*0.4 - 1.
// (round-4-verified: identical absmax to Cox-de-Boor recursion)
__device__ __forceinline__ void kan_bases(float x, float* __restrict__ b) {
    const float c6 = 0.166666666667f;
    float u  = fmaf(x, 2.5f, 5.5f);      // (x + 2.2) / 0.4
    float fj = floorf(u);
    float t  = u - fj;                    // in [0,1)
    int  j0  = (int)fj;
    float t2 = t * t, t3 = t2 * t;
    float n0 = t3 * c6;
    float n1 = fmaf(t3, -0.5f, fmaf(t2, 0.5f, fmaf(t, 0.5f, c6)));
    float n2 = fmaf(t3, 0.5f, fmaf(t2, -1.0f, 0.666666666667f));
    float omt = 1.0f - t;
    float n3 = omt * omt * omt * c6;
#pragma unroll
    for (int c = 0; c < 8; ++c) {
        int d = j0 - c;
        float v = (d == 0) ? n0 : 0.0f;
        v = (d == 1) ? n1 : v;
        v = (d == 2) ? n2 : v;
        v = (d == 3) ? n3 : v;
        b[c] = v;
    }
}

// ---- Merged prep: W' bf16 [768][6912] (blocks 0..767) and
//      F bf16 [16384][6912] (blocks 768..17151). Silu writes packed uint4.
__global__ __launch_bounds__(256) void prep_expand(
    const float* __restrict__ x, const float* __restrict__ bw,
    const float* __restrict__ sw, const float* __restrict__ sc,
    unsigned short* __restrict__ wp, unsigned short* __restrict__ F)
{
    const int b = blockIdx.x, t = threadIdx.x;
    if (b < H) {
        const int n = b;
        const float* bwr = bw + (size_t)n * H;
        unsigned short* out = wp + (size_t)n * KEXP;
        if (t < 96) {   // base_w: 96 packed uint4 writes
            const float4* xp = (const float4*)(bwr + t * 8);
            float4 v0 = xp[0], v1 = xp[1];
            uint4 pk;
            pk.x = pack2(f2bf(v0.x), f2bf(v0.y));
            pk.y = pack2(f2bf(v0.z), f2bf(v0.w));
            pk.z = pack2(f2bf(v1.x), f2bf(v1.y));
            pk.w = pack2(f2bf(v1.z), f2bf(v1.w));
            *(uint4*)(out + t * 8) = pk;
        }
#pragma unroll
        for (int p = 0; p < 3; ++p) {
            int i = t + p * 256;
            float s = sc[(size_t)n * H + i];
            const float4* swp = (const float4*)(sw + ((size_t)n * H + i) * 8);
            float4 w0 = swp[0], w1 = swp[1];
            uint4 pk;
            pk.x = pack2(f2bf(w0.x * s), f2bf(w0.y * s));
            pk.y = pack2(f2bf(w0.z * s), f2bf(w0.w * s));
            pk.z = pack2(f2bf(w1.x * s), f2bf(w1.y * s));
            pk.w = pack2(f2bf(w1.z * s), f2bf(w1.w * s));
            *(uint4*)(out + H + (size_t)i * 8) = pk;
        }
    } else {
        const int n = b - H;
        const float* xr = x + (size_t)n * H;
        unsigned short* out = F + (size_t)n * KEXP;
        if (t < 96) {   // silu: 96 packed uint4 writes
            const float4* xp = (const float4*)(xr + t * 8);
            float4 v0 = xp[0], v1 = xp[1];
            uint4 pk;
            pk.x = pack2(f2bf(silu_f(v0.x)), f2bf(silu_f(v0.y)));
            pk.y = pack2(f2bf(silu_f(v0.z)), f2bf(silu_f(v0.w)));
            pk.z = pack2(f2bf(silu_f(v1.x)), f2bf(silu_f(v1.y)));
            pk.w = pack2(f2bf(silu_f(v1.z)), f2bf(silu_f(v1.w)));
            *(uint4*)(out + t * 8) = pk;
        }
#pragma unroll
        for (int p = 0; p < 3; ++p) {
            int i = t + p * 256;
            float xv = xr[i];
            float bb[8];
            kan_bases(xv, bb);
            uint4 pk;
            pk.x = pack2(f2bf(bb[0]), f2bf(bb[1]));
            pk.y = pack2(f2bf(bb[2]), f2bf(bb[3]));
            pk.z = pack2(f2bf(bb[4]), f2bf(bb[5]));
            pk.w = pack2(f2bf(bb[6]), f2bf(bb[7]));
            *(uint4*)(out + H + (size_t)i * 8) = pk;
        }
    }
}

// ---- Layer 1: pure bf16 MFMA GEMM — R4 structure verbatim (VGPR 76, 213us).
// Epilogue is store-only (register-trivial): the 840TF plateau requires it (r7).
__global__ __launch_bounds__(256) void kan1_gemm(
    const unsigned short* __restrict__ F, const unsigned short* __restrict__ wp,
    unsigned short* __restrict__ l1)
{
    __shared__ __align__(16) unsigned short sA[128 * 64];
    __shared__ __align__(16) unsigned short sB[128 * 64];
    const int b = blockIdx.x;          // 0..767
    const int xcd = b & 7, s = b >> 3; // s in 0..95
    const int rowT = xcd * 16 + s / 6;
    const int colT = s % 6;
    const int rowBase = rowT * 128, colBase = colT * 128;

    const int t = threadIdx.x;
    const int lane = t & 63, wv = t >> 6;
    const int quad = lane >> 4, lm = lane & 15;
    const int wr = wv & 1, wc = wv >> 1;
    const int p7 = lm & 7;

    floatx4 acc[4][4] = {};
    int aoff[4], boff[4], goff[2];
#pragma unroll
    for (int im = 0; im < 4; ++im) aoff[im] = (wr * 64 + im * 16 + lm) * 64;
#pragma unroll
    for (int in_ = 0; in_ < 4; ++in_) boff[in_] = (wc * 64 + in_ * 16 + lm) * 64;
#pragma unroll
    for (int kk = 0; kk < 2; ++kk) goff[kk] = ((kk * 4 + quad) ^ p7) * 8;

    const int br_off = lane >> 3;   // row within 8-row segment
    const int bg_slot = lane & 7;   // lds granule slot

#pragma unroll 1
    for (int kc = 0; kc < NCHUNK; ++kc) {
#pragma unroll
        for (int p = 0; p < 4; ++p) {
            int sseg = wv * 4 + p;
            int r = sseg * 8 + br_off;
            int g = bg_slot ^ (r & 7);
            const unsigned short* ga = F  + (size_t)(rowBase + r) * KEXP + kc * 64 + g * 8;
            const unsigned short* gb = wp + (size_t)(colBase + r) * KEXP + kc * 64 + g * 8;
            __builtin_amdgcn_global_load_lds(
                (const __attribute__((address_space(1))) void*)ga,
                (__attribute__((address_space(3))) void*)(sA + sseg * 512), 16, 0, 0);
            __builtin_amdgcn_global_load_lds(
                (const __attribute__((address_space(1))) void*)gb,
                (__attribute__((address_space(3))) void*)(sB + sseg * 512), 16, 0, 0);
        }
        __syncthreads();
#pragma unroll
        for (int kk = 0; kk < 2; ++kk) {
            bhalf8 af[4], bf[4];
#pragma unroll
            for (int im = 0; im < 4; ++im) af[im] = *(const bhalf8*)&sA[aoff[im] + goff[kk]];
#pragma unroll
            for (int in_ = 0; in_ < 4; ++in_) bf[in_] = *(const bhalf8*)&sB[boff[in_] + goff[kk]];
#pragma unroll
            for (int im = 0; im < 4; ++im)
#pragma unroll
                for (int in_ = 0; in_ < 4; ++in_)
                    acc[im][in_] = __builtin_amdgcn_mfma_f32_16x16x32_bf16(
                        af[im], bf[in_], acc[im][in_], 0, 0, 0);
        }
        __syncthreads();
    }
#pragma unroll
    for (int im = 0; im < 4; ++im) {
#pragma unroll
        for (int in_ = 0; in_ < 4; ++in_) {
            int col = colBase + wc * 64 + in_ * 16 + lm;
            size_t rbase = (size_t)(rowBase + wr * 64 + im * 16 + quad * 4);
#pragma unroll
            for (int reg = 0; reg < 4; ++reg)
                l1[(rbase + reg) * H + col] = f2bf(acc[im][in_][reg]);
        }
    }
}

// ---- GELU pass: l1 <- gelu(l1), in-place, bhalf8 vectorized.
// 12.6M elems / 8 per thread = 1.57M threads = 6144 blocks. ~15us (50MB).
__global__ __launch_bounds__(256) void gelu_pass(unsigned short* __restrict__ l1)
{
    const size_t idx = ((size_t)blockIdx.x * 256 + threadIdx.x) * 8;
    bhalf8 v = *(const bhalf8*)&l1[idx];
    uint4 pk;
    float u0 = gelu_exact(bf2f((unsigned short)v[0]));
    float u1 = gelu_exact(bf2f((unsigned short)v[1]));
    float u2 = gelu_exact(bf2f((unsigned short)v[2]));
    float u3 = gelu_exact(bf2f((unsigned short)v[3]));
    float u4 = gelu_exact(bf2f((unsigned short)v[4]));
    float u5 = gelu_exact(bf2f((unsigned short)v[5]));
    float u6 = gelu_exact(bf2f((unsigned short)v[6]));
    float u7 = gelu_exact(bf2f((unsigned short)v[7]));
    pk.x = pack2(f2bf(u0), f2bf(u1));
    pk.y = pack2(f2bf(u2), f2bf(u3));
    pk.z = pack2(f2bf(u4), f2bf(u5));
    pk.w = pack2(f2bf(u6), f2bf(u7));
    *(uint4*)&l1[idx] = pk;
}

// ---- Layer 2 (no erf — gelu already applied): 8 rows/block, half-wave per
// row, bhalf8 vector loads of u, width-32 shuffle reduction.
__global__ __launch_bounds__(256) void kan2_kernel(
    const unsigned short* __restrict__ l1, const float* __restrict__ bw,
    const float* __restrict__ sw, const float* __restrict__ sc,
    float* __restrict__ out)
{
    const int t = threadIdx.x;
    const int half = t >> 5;          // 0..7 -> row within block
    const int lane32 = t & 31;
    const int n = blockIdx.x * 8 + half;
    float a0 = 0.f, a1 = 0.f;
#pragma unroll
    for (int it = 0; it < 3; ++it) {
        int c0 = (lane32 + it * 32) * 8;          // channel base (8 per lane)
        bhalf8 v = *(const bhalf8*)&l1[(size_t)n * H + c0];
#pragma unroll
        for (int j = 0; j < 8; ++j) {
            int i = c0 + j;
            float u = bf2f((unsigned short)v[j]);
            float f0 = silu_f(u);
            float bb[8];
            kan_bases(u, bb);
            float bw0 = bw[i], bw1 = bw[H + i];
            float s0 = sc[i], s1 = sc[H + i];
            const float4* q0 = (const float4*)(sw + (size_t)i * 8);
            const float4* q1 = (const float4*)(sw + (size_t)(H + i) * 8);
            float4 w00 = q0[0], w01 = q0[1];
            float4 w10 = q1[0], w11 = q1[1];
            float t0 = bb[0]*w00.x + bb[1]*w00.y + bb[2]*w00.z + bb[3]*w00.w
                     + bb[4]*w01.x + bb[5]*w01.y + bb[6]*w01.z + bb[7]*w01.w;
            float t1 = bb[0]*w10.x + bb[1]*w10.y + bb[2]*w10.z + bb[3]*w10.w
                     + bb[4]*w11.x + bb[5]*w11.y + bb[6]*w11.z + bb[7]*w11.w;
            a0 += f0 * bw0 + s0 * t0;
            a1 += f0 * bw1 + s1 * t1;
        }
    }
#pragma unroll
    for (int off = 16; off > 0; off >>= 1) {
        a0 += __shfl_down(a0, off, 32);
        a1 += __shfl_down(a1, off, 32);
    }
    if (lane32 == 0) {
        out[(size_t)n * 2 + 0] = a0;
        out[(size_t)n * 2 + 1] = a1;
    }
}

extern "C" void kernel_launch(void* const* d_in, const int* in_sizes, int n_in,
                              void* d_out, int out_size, void* d_ws, size_t ws_size,
                              hipStream_t stream) {
    const float* hidden = (const float*)d_in[0];
    const float* bw1    = (const float*)d_in[1];
    const float* sw1    = (const float*)d_in[2];
    const float* sc1    = (const float*)d_in[3];
    const float* bw2    = (const float*)d_in[4];
    const float* sw2    = (const float*)d_in[5];
    const float* sc2    = (const float*)d_in[6];
    float* out = (float*)d_out;

    // R4 workspace layout exactly: l1, wp, F
    const size_t l1_elems = (size_t)NROWS * H;     // 25.2 MB bf16
    const size_t wp_elems = (size_t)H * KEXP;      // 10.6 MB bf16
    unsigned short* l1 = (unsigned short*)d_ws;
    unsigned short* wp = l1 + l1_elems;
    unsigned short* F  = wp + wp_elems;            // 226.5 MB bf16

    prep_expand<<<H + NROWS, 256, 0, stream>>>(hidden, bw1, sw1, sc1, wp, F);
    kan1_gemm<<<768, 256, 0, stream>>>(F, wp, l1);
    gelu_pass<<<NROWS * H / (256 * 8), 256, 0, stream>>>(l1);
    kan2_kernel<<<NROWS / 8, 256, 0, stream>>>(l1, bw2, sw2, sc2, out);
}

// Round 9
// 437.923 us; speedup vs baseline: 1.4881x; 1.0369x over previous
//
#include <hip/hip_runtime.h>
#include <math.h>

// Problem constants
#define NROWS 16384   // 32*512
#define H     768
#define KEXP  6912    // 768 (silu*base_w) + 768*8 (bases*spline_w*scaler)
#define NCHUNK 108    // KEXP/64
#define K2ROWS 16     // rows per kan2 block

typedef __attribute__((ext_vector_type(8))) short  bhalf8;
typedef __attribute__((ext_vector_type(4))) float  floatx4;

__device__ __forceinline__ unsigned short f2bf(float f) {
    unsigned int u = __float_as_uint(f);
    u = (u + 0x7FFFu + ((u >> 16) & 1u)) >> 16;   // RNE
    return (unsigned short)u;
}
__device__ __forceinline__ float bf2f(unsigned short h) {
    return __uint_as_float(((unsigned int)h) << 16);
}
__device__ __forceinline__ unsigned int pack2(unsigned short a, unsigned short b) {
    return (unsigned int)a | ((unsigned int)b << 16);
}
__device__ __forceinline__ float silu_f(float x) { return x / (1.0f + __expf(-x)); }
__device__ __forceinline__ float gelu_exact(float x) {
    return 0.5f * x * (1.0f + erff(x * 0.70710678118654752f));
}

// Closed-form cubic B-spline bases on uniform knots g[j] = (j-3)*0.4 - 1.
// (round-4-verified: identical absmax to Cox-de-Boor recursion)
__device__ __forceinline__ void kan_bases(float x, float* __restrict__ b) {
    const float c6 = 0.166666666667f;
    float u  = fmaf(x, 2.5f, 5.5f);      // (x + 2.2) / 0.4
    float fj = floorf(u);
    float t  = u - fj;                    // in [0,1)
    int  j0  = (int)fj;
    float t2 = t * t, t3 = t2 * t;
    float n0 = t3 * c6;
    float n1 = fmaf(t3, -0.5f, fmaf(t2, 0.5f, fmaf(t, 0.5f, c6)));
    float n2 = fmaf(t3, 0.5f, fmaf(t2, -1.0f, 0.666666666667f));
    float omt = 1.0f - t;
    float n3 = omt * omt * omt * c6;
#pragma unroll
    for (int c = 0; c < 8; ++c) {
        int d = j0 - c;
        float v = (d == 0) ? n0 : 0.0f;
        v = (d == 1) ? n1 : v;
        v = (d == 2) ? n2 : v;
        v = (d == 3) ? n3 : v;
        b[c] = v;
    }
}

// LDS granule swizzle for per-channel 16B weight records (4-way conflict max)
__device__ __forceinline__ int wslot(int c) {
    return (c & ~7) | ((c & 7) ^ ((c >> 3) & 7));
}

// ---- Merged prep: W' bf16 [768][6912] (blocks 0..767) and
//      F bf16 [16384][6912] (blocks 768..17151). x staged via LDS (single read).
__global__ __launch_bounds__(256) void prep_expand(
    const float* __restrict__ x, const float* __restrict__ bw,
    const float* __restrict__ sw, const float* __restrict__ sc,
    unsigned short* __restrict__ wp, unsigned short* __restrict__ F)
{
    const int b = blockIdx.x, t = threadIdx.x;
    if (b < H) {
        const int n = b;
        const float* bwr = bw + (size_t)n * H;
        unsigned short* out = wp + (size_t)n * KEXP;
        if (t < 96) {   // base_w: 96 packed uint4 writes
            const float4* xp = (const float4*)(bwr + t * 8);
            float4 v0 = xp[0], v1 = xp[1];
            uint4 pk;
            pk.x = pack2(f2bf(v0.x), f2bf(v0.y));
            pk.y = pack2(f2bf(v0.z), f2bf(v0.w));
            pk.z = pack2(f2bf(v1.x), f2bf(v1.y));
            pk.w = pack2(f2bf(v1.z), f2bf(v1.w));
            *(uint4*)(out + t * 8) = pk;
        }
#pragma unroll
        for (int p = 0; p < 3; ++p) {
            int i = t + p * 256;
            float s = sc[(size_t)n * H + i];
            const float4* swp = (const float4*)(sw + ((size_t)n * H + i) * 8);
            float4 w0 = swp[0], w1 = swp[1];
            uint4 pk;
            pk.x = pack2(f2bf(w0.x * s), f2bf(w0.y * s));
            pk.y = pack2(f2bf(w0.z * s), f2bf(w0.w * s));
            pk.z = pack2(f2bf(w1.x * s), f2bf(w1.y * s));
            pk.w = pack2(f2bf(w1.z * s), f2bf(w1.w * s));
            *(uint4*)(out + H + (size_t)i * 8) = pk;
        }
    } else {
        const int n = b - H;
        __shared__ float sX[H];
        const float* xr = x + (size_t)n * H;
        if (t < 192) ((float4*)sX)[t] = ((const float4*)xr)[t];
        __syncthreads();
        unsigned short* out = F + (size_t)n * KEXP;
        if (t < 96) {   // silu: 96 packed uint4 writes
            const float4* xp = (const float4*)(sX + t * 8);
            float4 v0 = xp[0], v1 = xp[1];
            uint4 pk;
            pk.x = pack2(f2bf(silu_f(v0.x)), f2bf(silu_f(v0.y)));
            pk.y = pack2(f2bf(silu_f(v0.z)), f2bf(silu_f(v0.w)));
            pk.z = pack2(f2bf(silu_f(v1.x)), f2bf(silu_f(v1.y)));
            pk.w = pack2(f2bf(silu_f(v1.z)), f2bf(silu_f(v1.w)));
            *(uint4*)(out + t * 8) = pk;
        }
#pragma unroll
        for (int p = 0; p < 3; ++p) {
            int i = t + p * 256;
            float xv = sX[i];
            float bb[8];
            kan_bases(xv, bb);
            uint4 pk;
            pk.x = pack2(f2bf(bb[0]), f2bf(bb[1]));
            pk.y = pack2(f2bf(bb[2]), f2bf(bb[3]));
            pk.z = pack2(f2bf(bb[4]), f2bf(bb[5]));
            pk.w = pack2(f2bf(bb[6]), f2bf(bb[7]));
            *(uint4*)(out + H + (size_t)i * 8) = pk;
        }
    }
}

// ---- Layer 1: pure bf16 MFMA GEMM — R4/R8 structure verbatim (VGPR 76, ~206us).
// Epilogue is store-only (register-trivial): the 840TF plateau requires it (r7).
__global__ __launch_bounds__(256) void kan1_gemm(
    const unsigned short* __restrict__ F, const unsigned short* __restrict__ wp,
    unsigned short* __restrict__ l1)
{
    __shared__ __align__(16) unsigned short sA[128 * 64];
    __shared__ __align__(16) unsigned short sB[128 * 64];
    const int b = blockIdx.x;          // 0..767
    const int xcd = b & 7, s = b >> 3; // s in 0..95
    const int rowT = xcd * 16 + s / 6;
    const int colT = s % 6;
    const int rowBase = rowT * 128, colBase = colT * 128;

    const int t = threadIdx.x;
    const int lane = t & 63, wv = t >> 6;
    const int quad = lane >> 4, lm = lane & 15;
    const int wr = wv & 1, wc = wv >> 1;
    const int p7 = lm & 7;

    floatx4 acc[4][4] = {};
    int aoff[4], boff[4], goff[2];
#pragma unroll
    for (int im = 0; im < 4; ++im) aoff[im] = (wr * 64 + im * 16 + lm) * 64;
#pragma unroll
    for (int in_ = 0; in_ < 4; ++in_) boff[in_] = (wc * 64 + in_ * 16 + lm) * 64;
#pragma unroll
    for (int kk = 0; kk < 2; ++kk) goff[kk] = ((kk * 4 + quad) ^ p7) * 8;

    const int br_off = lane >> 3;   // row within 8-row segment
    const int bg_slot = lane & 7;   // lds granule slot

#pragma unroll 1
    for (int kc = 0; kc < NCHUNK; ++kc) {
#pragma unroll
        for (int p = 0; p < 4; ++p) {
            int sseg = wv * 4 + p;
            int r = sseg * 8 + br_off;
            int g = bg_slot ^ (r & 7);
            const unsigned short* ga = F  + (size_t)(rowBase + r) * KEXP + kc * 64 + g * 8;
            const unsigned short* gb = wp + (size_t)(colBase + r) * KEXP + kc * 64 + g * 8;
            __builtin_amdgcn_global_load_lds(
                (const __attribute__((address_space(1))) void*)ga,
                (__attribute__((address_space(3))) void*)(sA + sseg * 512), 16, 0, 0);
            __builtin_amdgcn_global_load_lds(
                (const __attribute__((address_space(1))) void*)gb,
                (__attribute__((address_space(3))) void*)(sB + sseg * 512), 16, 0, 0);
        }
        __syncthreads();
#pragma unroll
        for (int kk = 0; kk < 2; ++kk) {
            bhalf8 af[4], bf[4];
#pragma unroll
            for (int im = 0; im < 4; ++im) af[im] = *(const bhalf8*)&sA[aoff[im] + goff[kk]];
#pragma unroll
            for (int in_ = 0; in_ < 4; ++in_) bf[in_] = *(const bhalf8*)&sB[boff[in_] + goff[kk]];
#pragma unroll
            for (int im = 0; im < 4; ++im)
#pragma unroll
                for (int in_ = 0; in_ < 4; ++in_)
                    acc[im][in_] = __builtin_amdgcn_mfma_f32_16x16x32_bf16(
                        af[im], bf[in_], acc[im][in_], 0, 0, 0);
        }
        __syncthreads();
    }
#pragma unroll
    for (int im = 0; im < 4; ++im) {
#pragma unroll
        for (int in_ = 0; in_ < 4; ++in_) {
            int col = colBase + wc * 64 + in_ * 16 + lm;
            size_t rbase = (size_t)(rowBase + wr * 64 + im * 16 + quad * 4);
#pragma unroll
            for (int reg = 0; reg < 4; ++reg)
                l1[(rbase + reg) * H + col] = f2bf(acc[im][in_][reg]);
        }
    }
}

// ---- Layer 2 v3: GELU fused, weights in LDS (bf16, scaler folded, swizzled).
// 16 rows/block, half-wave per row, bhalf8 h loads, width-32 shuffle reduce.
// LDS 27KB -> 5 blocks/CU.
__global__ __launch_bounds__(256) void kan2_kernel(
    const unsigned short* __restrict__ l1, const float* __restrict__ bw2,
    const float* __restrict__ sw2, const float* __restrict__ sc2,
    float* __restrict__ out)
{
    __shared__ __align__(16) unsigned short sW0[H * 8];  // 12 KB
    __shared__ __align__(16) unsigned short sW1[H * 8];  // 12 KB
    __shared__ unsigned int sBW[H];                      // 3 KB (bw0,bw1 bf16 pair)
    const int t = threadIdx.x;

    // stage weights: 3 channels per thread
    for (int c = t; c < H; c += 256) {
        int slot = wslot(c) * 8;
        {
            float s = sc2[c];
            const float4* q = (const float4*)(sw2 + (size_t)c * 8);
            float4 a = q[0], b = q[1];
            uint4 pk;
            pk.x = pack2(f2bf(a.x * s), f2bf(a.y * s));
            pk.y = pack2(f2bf(a.z * s), f2bf(a.w * s));
            pk.z = pack2(f2bf(b.x * s), f2bf(b.y * s));
            pk.w = pack2(f2bf(b.z * s), f2bf(b.w * s));
            *(uint4*)&sW0[slot] = pk;
        }
        {
            float s = sc2[H + c];
            const float4* q = (const float4*)(sw2 + (size_t)(H + c) * 8);
            float4 a = q[0], b = q[1];
            uint4 pk;
            pk.x = pack2(f2bf(a.x * s), f2bf(a.y * s));
            pk.y = pack2(f2bf(a.z * s), f2bf(a.w * s));
            pk.z = pack2(f2bf(b.x * s), f2bf(b.y * s));
            pk.w = pack2(f2bf(b.z * s), f2bf(b.w * s));
            *(uint4*)&sW1[slot] = pk;
        }
        sBW[c] = pack2(f2bf(bw2[c]), f2bf(bw2[H + c]));
    }
    __syncthreads();

    const int half = t >> 5;          // 0..7 -> row within group
    const int lane32 = t & 31;
#pragma unroll
    for (int g = 0; g < K2ROWS / 8; ++g) {
        const int n = blockIdx.x * K2ROWS + g * 8 + half;
        float a0 = 0.f, a1 = 0.f;
#pragma unroll
        for (int it = 0; it < 3; ++it) {
            int c0 = (lane32 + it * 32) * 8;          // 8 consecutive channels
            bhalf8 v = *(const bhalf8*)&l1[(size_t)n * H + c0];
#pragma unroll
            for (int j = 0; j < 8; ++j) {
                int c = c0 + j;
                float h = bf2f((unsigned short)v[j]);
                float u = gelu_exact(h);
                float f0 = silu_f(u);
                float bb[8];
                kan_bases(u, bb);
                int slot = wslot(c) * 8;
                bhalf8 w0 = *(const bhalf8*)&sW0[slot];
                bhalf8 w1 = *(const bhalf8*)&sW1[slot];
                unsigned int bwp = sBW[c];
                float t0 = 0.f, t1 = 0.f;
#pragma unroll
                for (int k = 0; k < 8; ++k) {
                    t0 = fmaf(bb[k], bf2f((unsigned short)w0[k]), t0);
                    t1 = fmaf(bb[k], bf2f((unsigned short)w1[k]), t1);
                }
                a0 += fmaf(f0, bf2f((unsigned short)(bwp & 0xFFFF)), t0);
                a1 += fmaf(f0, bf2f((unsigned short)(bwp >> 16)), t1);
            }
        }
#pragma unroll
        for (int off = 16; off > 0; off >>= 1) {
            a0 += __shfl_down(a0, off, 32);
            a1 += __shfl_down(a1, off, 32);
        }
        if (lane32 == 0) {
            out[(size_t)n * 2 + 0] = a0;
            out[(size_t)n * 2 + 1] = a1;
        }
    }
}

extern "C" void kernel_launch(void* const* d_in, const int* in_sizes, int n_in,
                              void* d_out, int out_size, void* d_ws, size_t ws_size,
                              hipStream_t stream) {
    const float* hidden = (const float*)d_in[0];
    const float* bw1    = (const float*)d_in[1];
    const float* sw1    = (const float*)d_in[2];
    const float* sc1    = (const float*)d_in[3];
    const float* bw2    = (const float*)d_in[4];
    const float* sw2    = (const float*)d_in[5];
    const float* sc2    = (const float*)d_in[6];
    float* out = (float*)d_out;

    // R4/R8 workspace layout exactly: l1, wp, F
    const size_t l1_elems = (size_t)NROWS * H;     // 25.2 MB bf16
    const size_t wp_elems = (size_t)H * KEXP;      // 10.6 MB bf16
    unsigned short* l1 = (unsigned short*)d_ws;
    unsigned short* wp = l1 + l1_elems;
    unsigned short* F  = wp + wp_elems;            // 226.5 MB bf16

    prep_expand<<<H + NROWS, 256, 0, stream>>>(hidden, bw1, sw1, sc1, wp, F);
    kan1_gemm<<<768, 256, 0, stream>>>(F, wp, l1);
    kan2_kernel<<<NROWS / K2ROWS, 256, 0, stream>>>(l1, bw2, sw2, sc2, out);
}

// Round 10
// 387.297 us; speedup vs baseline: 1.6826x; 1.1307x over previous
//
#include <hip/hip_runtime.h>
#include <math.h>

// Problem constants
#define NROWS 16384   // 32*512
#define H     768
#define KEXP  6912    // 768 (silu*base_w) + 768*8 (bases*spline_w*scaler)
#define NCHUNK 108    // KEXP/64

typedef __attribute__((ext_vector_type(8))) short  bhalf8;
typedef __attribute__((ext_vector_type(4))) float  floatx4;

__device__ __forceinline__ unsigned short f2bf(float f) {
    unsigned int u = __float_as_uint(f);
    u = (u + 0x7FFFu + ((u >> 16) & 1u)) >> 16;   // RNE
    return (unsigned short)u;
}
__device__ __forceinline__ float bf2f(unsigned short h) {
    return __uint_as_float(((unsigned int)h) << 16);
}
__device__ __forceinline__ unsigned int pack2(unsigned short a, unsigned short b) {
    return (unsigned int)a | ((unsigned int)b << 16);
}
__device__ __forceinline__ float silu_f(float x) { return x / (1.0f + __expf(-x)); }

// Branch-free tanh-form GELU (|err vs exact erf-GELU| < ~1e-3 in u;
// output sensitivity ~sqrt(768)*0.3*eps -> <0.01 on final out, vs 0.42 budget).
__device__ __forceinline__ float gelu_fast(float x) {
    float x3 = x * x * x;
    float y = fmaf(x3, 0.0356774081f, x * 0.7978845608f);  // sqrt(2/pi)*(x+0.044715x^3)
    float e = __expf(2.0f * y);
    float th = 1.0f - 2.0f / (e + 1.0f);    // tanh(y); e->inf => 1, e->0 => -1
    return 0.5f * x * (1.0f + th);
}

// Closed-form cubic B-spline bases on uniform knots g[j] = (j-3)*0.4 - 1.
// (round-4-verified: identical absmax to Cox-de-Boor recursion)
__device__ __forceinline__ void kan_bases(float x, float* __restrict__ b) {
    const float c6 = 0.166666666667f;
    float u  = fmaf(x, 2.5f, 5.5f);      // (x + 2.2) / 0.4
    float fj = floorf(u);
    float t  = u - fj;                    // in [0,1)
    int  j0  = (int)fj;
    float t2 = t * t, t3 = t2 * t;
    float n0 = t3 * c6;
    float n1 = fmaf(t3, -0.5f, fmaf(t2, 0.5f, fmaf(t, 0.5f, c6)));
    float n2 = fmaf(t3, 0.5f, fmaf(t2, -1.0f, 0.666666666667f));
    float omt = 1.0f - t;
    float n3 = omt * omt * omt * c6;
#pragma unroll
    for (int c = 0; c < 8; ++c) {
        int d = j0 - c;
        float v = (d == 0) ? n0 : 0.0f;
        v = (d == 1) ? n1 : v;
        v = (d == 2) ? n2 : v;
        v = (d == 3) ? n3 : v;
        b[c] = v;
    }
}

// ---- Merged prep: W' bf16 [768][6912] (blocks 0..767) and
//      F bf16 [16384][6912] (blocks 768..17151). x staged via LDS (single read).
__global__ __launch_bounds__(256) void prep_expand(
    const float* __restrict__ x, const float* __restrict__ bw,
    const float* __restrict__ sw, const float* __restrict__ sc,
    unsigned short* __restrict__ wp, unsigned short* __restrict__ F)
{
    const int b = blockIdx.x, t = threadIdx.x;
    if (b < H) {
        const int n = b;
        const float* bwr = bw + (size_t)n * H;
        unsigned short* out = wp + (size_t)n * KEXP;
        if (t < 96) {   // base_w: 96 packed uint4 writes
            const float4* xp = (const float4*)(bwr + t * 8);
            float4 v0 = xp[0], v1 = xp[1];
            uint4 pk;
            pk.x = pack2(f2bf(v0.x), f2bf(v0.y));
            pk.y = pack2(f2bf(v0.z), f2bf(v0.w));
            pk.z = pack2(f2bf(v1.x), f2bf(v1.y));
            pk.w = pack2(f2bf(v1.z), f2bf(v1.w));
            *(uint4*)(out + t * 8) = pk;
        }
#pragma unroll
        for (int p = 0; p < 3; ++p) {
            int i = t + p * 256;
            float s = sc[(size_t)n * H + i];
            const float4* swp = (const float4*)(sw + ((size_t)n * H + i) * 8);
            float4 w0 = swp[0], w1 = swp[1];
            uint4 pk;
            pk.x = pack2(f2bf(w0.x * s), f2bf(w0.y * s));
            pk.y = pack2(f2bf(w0.z * s), f2bf(w0.w * s));
            pk.z = pack2(f2bf(w1.x * s), f2bf(w1.y * s));
            pk.w = pack2(f2bf(w1.z * s), f2bf(w1.w * s));
            *(uint4*)(out + H + (size_t)i * 8) = pk;
        }
    } else {
        const int n = b - H;
        __shared__ float sX[H];
        const float* xr = x + (size_t)n * H;
        if (t < 192) ((float4*)sX)[t] = ((const float4*)xr)[t];
        __syncthreads();
        unsigned short* out = F + (size_t)n * KEXP;
        if (t < 96) {   // silu: 96 packed uint4 writes
            const float4* xp = (const float4*)(sX + t * 8);
            float4 v0 = xp[0], v1 = xp[1];
            uint4 pk;
            pk.x = pack2(f2bf(silu_f(v0.x)), f2bf(silu_f(v0.y)));
            pk.y = pack2(f2bf(silu_f(v0.z)), f2bf(silu_f(v0.w)));
            pk.z = pack2(f2bf(silu_f(v1.x)), f2bf(silu_f(v1.y)));
            pk.w = pack2(f2bf(silu_f(v1.z)), f2bf(silu_f(v1.w)));
            *(uint4*)(out + t * 8) = pk;
        }
#pragma unroll
        for (int p = 0; p < 3; ++p) {
            int i = t + p * 256;
            float xv = sX[i];
            float bb[8];
            kan_bases(xv, bb);
            uint4 pk;
            pk.x = pack2(f2bf(bb[0]), f2bf(bb[1]));
            pk.y = pack2(f2bf(bb[2]), f2bf(bb[3]));
            pk.z = pack2(f2bf(bb[4]), f2bf(bb[5]));
            pk.w = pack2(f2bf(bb[6]), f2bf(bb[7]));
            *(uint4*)(out + H + (size_t)i * 8) = pk;
        }
    }
}

// ---- Layer 1: pure bf16 MFMA GEMM — R4/R8/R9 structure verbatim (VGPR 76, ~206us).
// Epilogue is store-only (register-trivial): the 840TF plateau requires it (r7).
__global__ __launch_bounds__(256) void kan1_gemm(
    const unsigned short* __restrict__ F, const unsigned short* __restrict__ wp,
    unsigned short* __restrict__ l1)
{
    __shared__ __align__(16) unsigned short sA[128 * 64];
    __shared__ __align__(16) unsigned short sB[128 * 64];
    const int b = blockIdx.x;          // 0..767
    const int xcd = b & 7, s = b >> 3; // s in 0..95
    const int rowT = xcd * 16 + s / 6;
    const int colT = s % 6;
    const int rowBase = rowT * 128, colBase = colT * 128;

    const int t = threadIdx.x;
    const int lane = t & 63, wv = t >> 6;
    const int quad = lane >> 4, lm = lane & 15;
    const int wr = wv & 1, wc = wv >> 1;
    const int p7 = lm & 7;

    floatx4 acc[4][4] = {};
    int aoff[4], boff[4], goff[2];
#pragma unroll
    for (int im = 0; im < 4; ++im) aoff[im] = (wr * 64 + im * 16 + lm) * 64;
#pragma unroll
    for (int in_ = 0; in_ < 4; ++in_) boff[in_] = (wc * 64 + in_ * 16 + lm) * 64;
#pragma unroll
    for (int kk = 0; kk < 2; ++kk) goff[kk] = ((kk * 4 + quad) ^ p7) * 8;

    const int br_off = lane >> 3;   // row within 8-row segment
    const int bg_slot = lane & 7;   // lds granule slot

#pragma unroll 1
    for (int kc = 0; kc < NCHUNK; ++kc) {
#pragma unroll
        for (int p = 0; p < 4; ++p) {
            int sseg = wv * 4 + p;
            int r = sseg * 8 + br_off;
            int g = bg_slot ^ (r & 7);
            const unsigned short* ga = F  + (size_t)(rowBase + r) * KEXP + kc * 64 + g * 8;
            const unsigned short* gb = wp + (size_t)(colBase + r) * KEXP + kc * 64 + g * 8;
            __builtin_amdgcn_global_load_lds(
                (const __attribute__((address_space(1))) void*)ga,
                (__attribute__((address_space(3))) void*)(sA + sseg * 512), 16, 0, 0);
            __builtin_amdgcn_global_load_lds(
                (const __attribute__((address_space(1))) void*)gb,
                (__attribute__((address_space(3))) void*)(sB + sseg * 512), 16, 0, 0);
        }
        __syncthreads();
#pragma unroll
        for (int kk = 0; kk < 2; ++kk) {
            bhalf8 af[4], bf[4];
#pragma unroll
            for (int im = 0; im < 4; ++im) af[im] = *(const bhalf8*)&sA[aoff[im] + goff[kk]];
#pragma unroll
            for (int in_ = 0; in_ < 4; ++in_) bf[in_] = *(const bhalf8*)&sB[boff[in_] + goff[kk]];
#pragma unroll
            for (int im = 0; im < 4; ++im)
#pragma unroll
                for (int in_ = 0; in_ < 4; ++in_)
                    acc[im][in_] = __builtin_amdgcn_mfma_f32_16x16x32_bf16(
                        af[im], bf[in_], acc[im][in_], 0, 0, 0);
        }
        __syncthreads();
    }
#pragma unroll
    for (int im = 0; im < 4; ++im) {
#pragma unroll
        for (int in_ = 0; in_ < 4; ++in_) {
            int col = colBase + wc * 64 + in_ * 16 + lm;
            size_t rbase = (size_t)(rowBase + wr * 64 + im * 16 + quad * 4);
#pragma unroll
            for (int reg = 0; reg < 4; ++reg)
                l1[(rbase + reg) * H + col] = f2bf(acc[im][in_][reg]);
        }
    }
}

// ---- Layer 2: R5's measured-fast shape (4 rows/block -> 4096 blocks = 16/CU,
// wave per row, global float4 weight loads) + branch-free GELU inline.
__global__ __launch_bounds__(256) void kan2_kernel(
    const unsigned short* __restrict__ l1, const float* __restrict__ bw,
    const float* __restrict__ sw, const float* __restrict__ sc,
    float* __restrict__ out)
{
    const int lane = threadIdx.x & 63;
    const int wv = threadIdx.x >> 6;
    const int n = blockIdx.x * 4 + wv;
    float a0 = 0.f, a1 = 0.f;
#pragma unroll
    for (int ii = 0; ii < H / 64; ++ii) {
        int i = lane + ii * 64;
        float h = bf2f(l1[(size_t)n * H + i]);
        float u = gelu_fast(h);
        float f0 = silu_f(u);
        float bb[8];
        kan_bases(u, bb);
        float bw0 = bw[i], bw1 = bw[H + i];
        float s0 = sc[i], s1 = sc[H + i];
        const float4* q0 = (const float4*)(sw + (size_t)i * 8);
        const float4* q1 = (const float4*)(sw + (size_t)(H + i) * 8);
        float4 w00 = q0[0], w01 = q0[1];
        float4 w10 = q1[0], w11 = q1[1];
        float t0 = bb[0]*w00.x + bb[1]*w00.y + bb[2]*w00.z + bb[3]*w00.w
                 + bb[4]*w01.x + bb[5]*w01.y + bb[6]*w01.z + bb[7]*w01.w;
        float t1 = bb[0]*w10.x + bb[1]*w10.y + bb[2]*w10.z + bb[3]*w10.w
                 + bb[4]*w11.x + bb[5]*w11.y + bb[6]*w11.z + bb[7]*w11.w;
        a0 += f0 * bw0 + s0 * t0;
        a1 += f0 * bw1 + s1 * t1;
    }
#pragma unroll
    for (int off = 32; off > 0; off >>= 1) {
        a0 += __shfl_down(a0, off, 64);
        a1 += __shfl_down(a1, off, 64);
    }
    if (lane == 0) {
        out[(size_t)n * 2 + 0] = a0;
        out[(size_t)n * 2 + 1] = a1;
    }
}

extern "C" void kernel_launch(void* const* d_in, const int* in_sizes, int n_in,
                              void* d_out, int out_size, void* d_ws, size_t ws_size,
                              hipStream_t stream) {
    const float* hidden = (const float*)d_in[0];
    const float* bw1    = (const float*)d_in[1];
    const float* sw1    = (const float*)d_in[2];
    const float* sc1    = (const float*)d_in[3];
    const float* bw2    = (const float*)d_in[4];
    const float* sw2    = (const float*)d_in[5];
    const float* sc2    = (const float*)d_in[6];
    float* out = (float*)d_out;

    // R4/R8/R9 workspace layout exactly: l1, wp, F
    const size_t l1_elems = (size_t)NROWS * H;     // 25.2 MB bf16
    const size_t wp_elems = (size_t)H * KEXP;      // 10.6 MB bf16
    unsigned short* l1 = (unsigned short*)d_ws;
    unsigned short* wp = l1 + l1_elems;
    unsigned short* F  = wp + wp_elems;            // 226.5 MB bf16

    prep_expand<<<H + NROWS, 256, 0, stream>>>(hidden, bw1, sw1, sc1, wp, F);
    kan1_gemm<<<768, 256, 0, stream>>>(F, wp, l1);
    kan2_kernel<<<NROWS / 4, 256, 0, stream>>>(l1, bw2, sw2, sc2, out);
}